// Round 1
// baseline (3653.988 us; speedup 1.0000x reference)
//
#include <hip/hip_runtime.h>
#include <hip/hip_bf16.h>
#include <math.h>

// ---------------------------------------------------------------------------
// 3-layer GCN (PyG GCNConv semantics, no self loops):
//   deg[i] = #incoming edges; dinv = deg>0 ? rsqrt(deg) : 0
//   norm_e = dinv[src]*dinv[dst]
//   per layer: h = act @ W ; out_i = sum_{e: dst=i} norm_e * h[src_e] + b ; ELU
// Pipeline: device-side CSR build (deg -> exclusive scan -> fill), then
// GEMM (f32 vector, LDS-tiled) + per-node wave aggregation, x3.
// Ping-pong: ws bufA <-> d_out (d_out fully overwritten each time; final
// aggregation writes d_out).
// ---------------------------------------------------------------------------

#define THREADS 256

__global__ void k_deg(const int* __restrict__ dst, int* __restrict__ deg, int E) {
    int e = blockIdx.x * THREADS + threadIdx.x;
    if (e < E) atomicAdd(&deg[dst[e]], 1);
}

__global__ void k_dinv(const int* __restrict__ deg, float* __restrict__ dinv, int N) {
    int i = blockIdx.x * THREADS + threadIdx.x;
    if (i < N) {
        int d = deg[i];
        dinv[i] = (d > 0) ? rsqrtf((float)d) : 0.0f;
    }
}

// exclusive scan of deg -> rowp, 3-pass
__global__ void k_scan1(const int* __restrict__ deg, int* __restrict__ rowp,
                        int* __restrict__ bsums, int N) {
    __shared__ int s[THREADS];
    int idx = blockIdx.x * THREADS + threadIdx.x;
    int v = (idx < N) ? deg[idx] : 0;
    s[threadIdx.x] = v;
    __syncthreads();
    for (int off = 1; off < THREADS; off <<= 1) {
        int t = (threadIdx.x >= off) ? s[threadIdx.x - off] : 0;
        __syncthreads();
        s[threadIdx.x] += t;
        __syncthreads();
    }
    if (idx < N) rowp[idx] = s[threadIdx.x] - v;   // exclusive
    if (threadIdx.x == THREADS - 1) bsums[blockIdx.x] = s[threadIdx.x];
}

__global__ void k_scan2(int* __restrict__ bsums, int NB) {
    __shared__ int s[512];
    int v = (threadIdx.x < NB) ? bsums[threadIdx.x] : 0;
    s[threadIdx.x] = v;
    __syncthreads();
    for (int off = 1; off < 512; off <<= 1) {
        int t = (threadIdx.x >= (unsigned)off) ? s[threadIdx.x - off] : 0;
        __syncthreads();
        s[threadIdx.x] += t;
        __syncthreads();
    }
    if (threadIdx.x < NB) bsums[threadIdx.x] = s[threadIdx.x] - v;  // exclusive
}

__global__ void k_scan3(int* __restrict__ rowp, const int* __restrict__ bsums, int N) {
    int idx = blockIdx.x * THREADS + threadIdx.x;
    if (idx < N) rowp[idx] += bsums[blockIdx.x];
}

__global__ void k_fill(const int* __restrict__ src, const int* __restrict__ dst,
                       const float* __restrict__ dinv, const int* __restrict__ rowp,
                       int* __restrict__ cnt, int* __restrict__ esrc,
                       float* __restrict__ enorm, int E) {
    int e = blockIdx.x * THREADS + threadIdx.x;
    if (e >= E) return;
    int s = src[e], d = dst[e];
    int pos = rowp[d] + atomicAdd(&cnt[d], 1);
    esrc[pos]  = s;
    enorm[pos] = dinv[s] * dinv[d];
}

// C[N,256] = X[N,K] @ W[K,256], f32 vector ALU, BM=64 BN=256 BK=32.
// Block = 256 threads: tc = tid&63 (4 cols each), tr = tid>>6 (16 rows each).
template <int K>
__global__ __launch_bounds__(256) void k_gemm(const float* __restrict__ X,
                                              const float* __restrict__ W,
                                              float* __restrict__ C, int N) {
    __shared__ float Xs[64 * 32];    // [r][k]  8 KB
    __shared__ float Ws[32 * 256];   // [k][c] 32 KB
    const int tid = threadIdx.x;
    const int tc = tid & 63;
    const int tr = tid >> 6;
    const int row0 = blockIdx.x * 64;

    float acc[16][4];
#pragma unroll
    for (int r = 0; r < 16; ++r)
#pragma unroll
        for (int j = 0; j < 4; ++j) acc[r][j] = 0.0f;

    for (int k0 = 0; k0 < K; k0 += 32) {
        // stage X tile: 512 float4
#pragma unroll
        for (int j = 0; j < 2; ++j) {
            int i  = tid + j * 256;        // 0..511
            int r  = i >> 3;               // 8 float4 per row
            int k4 = i & 7;
            int gr = row0 + r;
            if (gr >= N) gr = N - 1;       // clamp (values unused)
            float4 v = *(const float4*)&X[(size_t)gr * K + k0 + k4 * 4];
            *(float4*)&Xs[r * 32 + k4 * 4] = v;
        }
        // stage W tile: 2048 float4
#pragma unroll
        for (int j = 0; j < 8; ++j) {
            int i  = tid + j * 256;        // 0..2047
            int kk = i >> 6;               // 64 float4 per row of 256
            int c4 = i & 63;
            float4 v = *(const float4*)&W[(size_t)(k0 + kk) * 256 + c4 * 4];
            *(float4*)&Ws[kk * 256 + c4 * 4] = v;
        }
        __syncthreads();

#pragma unroll
        for (int kk = 0; kk < 32; kk += 4) {
            float4 w0 = *(const float4*)&Ws[(kk + 0) * 256 + tc * 4];
            float4 w1 = *(const float4*)&Ws[(kk + 1) * 256 + tc * 4];
            float4 w2 = *(const float4*)&Ws[(kk + 2) * 256 + tc * 4];
            float4 w3 = *(const float4*)&Ws[(kk + 3) * 256 + tc * 4];
#pragma unroll
            for (int rr = 0; rr < 16; ++rr) {
                float4 xv = *(const float4*)&Xs[(tr * 16 + rr) * 32 + kk];
                acc[rr][0] += xv.x * w0.x + xv.y * w1.x + xv.z * w2.x + xv.w * w3.x;
                acc[rr][1] += xv.x * w0.y + xv.y * w1.y + xv.z * w2.y + xv.w * w3.y;
                acc[rr][2] += xv.x * w0.z + xv.y * w1.z + xv.z * w2.z + xv.w * w3.z;
                acc[rr][3] += xv.x * w0.w + xv.y * w1.w + xv.z * w2.w + xv.w * w3.w;
            }
        }
        __syncthreads();
    }

#pragma unroll
    for (int rr = 0; rr < 16; ++rr) {
        int gr = row0 + tr * 16 + rr;
        if (gr < N) {
            *(float4*)&C[(size_t)gr * 256 + tc * 4] =
                make_float4(acc[rr][0], acc[rr][1], acc[rr][2], acc[rr][3]);
        }
    }
}

__device__ __forceinline__ float elu1(float x) {
    return x > 0.0f ? x : expm1f(x);
}

// one wave per node; lane handles 4 channels (float4).
__global__ __launch_bounds__(256) void k_agg(const float* __restrict__ h,
                                             const int* __restrict__ rowp,
                                             const int* __restrict__ deg,
                                             const int* __restrict__ esrc,
                                             const float* __restrict__ enorm,
                                             const float* __restrict__ bias,
                                             float* __restrict__ out, int N) {
    int wave = threadIdx.x >> 6;
    int lane = threadIdx.x & 63;
    int node = blockIdx.x * 4 + wave;
    if (node >= N) return;

    int start = rowp[node];
    int cnt   = deg[node];

    float4 acc = make_float4(0.f, 0.f, 0.f, 0.f);
    for (int e = 0; e < cnt; ++e) {
        int   s   = esrc[start + e];
        float nrm = enorm[start + e];
        float4 hv = *(const float4*)&h[(size_t)s * 256 + lane * 4];
        acc.x += nrm * hv.x;
        acc.y += nrm * hv.y;
        acc.z += nrm * hv.z;
        acc.w += nrm * hv.w;
    }
    float4 b4 = *(const float4*)&bias[lane * 4];
    float4 o;
    o.x = elu1(acc.x + b4.x);
    o.y = elu1(acc.y + b4.y);
    o.z = elu1(acc.z + b4.z);
    o.w = elu1(acc.w + b4.w);
    *(float4*)&out[(size_t)node * 256 + lane * 4] = o;
}

static inline size_t alignup(size_t x) { return (x + 255) & ~(size_t)255; }

extern "C" void kernel_launch(void* const* d_in, const int* in_sizes, int n_in,
                              void* d_out, int out_size, void* d_ws, size_t ws_size,
                              hipStream_t stream) {
    const float* x  = (const float*)d_in[0];
    const int*   ei = (const int*)d_in[1];
    const float* W1 = (const float*)d_in[2];
    const float* b1 = (const float*)d_in[3];
    const float* W2 = (const float*)d_in[4];
    const float* b2 = (const float*)d_in[5];
    const float* W3 = (const float*)d_in[6];
    const float* b3 = (const float*)d_in[7];
    float* out = (float*)d_out;

    const int N = in_sizes[0] / 64;   // 100000
    const int E = in_sizes[1] / 2;    // 600000
    const int* src = ei;
    const int* dst = ei + E;

    // workspace carve
    char* p = (char*)d_ws;
    int*   deg   = (int*)p;   p += alignup((size_t)N * 4);
    float* dinv  = (float*)p; p += alignup((size_t)N * 4);
    int*   rowp  = (int*)p;   p += alignup((size_t)N * 4);
    int*   cnt   = (int*)p;   p += alignup((size_t)N * 4);
    int*   esrc  = (int*)p;   p += alignup((size_t)E * 4);
    float* enorm = (float*)p; p += alignup((size_t)E * 4);
    const int NB = (N + THREADS - 1) / THREADS;
    int*   bsums = (int*)p;   p += alignup((size_t)NB * 4);
    float* bufA  = (float*)p; p += alignup((size_t)N * 256 * 4);

    const int EB = (E + THREADS - 1) / THREADS;
    const int GB = (N + 63) / 64;       // gemm blocks
    const int AB = (N + 3) / 4;         // agg blocks (4 waves/block)

    hipMemsetAsync(deg, 0, (size_t)N * 4, stream);
    hipMemsetAsync(cnt, 0, (size_t)N * 4, stream);

    k_deg<<<EB, THREADS, 0, stream>>>(dst, deg, E);
    k_dinv<<<NB, THREADS, 0, stream>>>(deg, dinv, N);
    k_scan1<<<NB, THREADS, 0, stream>>>(deg, rowp, bsums, N);
    k_scan2<<<1, 512, 0, stream>>>(bsums, NB);
    k_scan3<<<NB, THREADS, 0, stream>>>(rowp, bsums, N);
    k_fill<<<EB, THREADS, 0, stream>>>(src, dst, dinv, rowp, cnt, esrc, enorm, E);

    // layer 1: x[N,64] @ W1 -> bufA ; agg -> d_out
    k_gemm<64><<<GB, THREADS, 0, stream>>>(x, W1, bufA, N);
    k_agg<<<AB, THREADS, 0, stream>>>(bufA, rowp, deg, esrc, enorm, b1, out, N);
    // layer 2: d_out @ W2 -> bufA ; agg -> d_out
    k_gemm<256><<<GB, THREADS, 0, stream>>>(out, W2, bufA, N);
    k_agg<<<AB, THREADS, 0, stream>>>(bufA, rowp, deg, esrc, enorm, b2, out, N);
    // layer 3
    k_gemm<256><<<GB, THREADS, 0, stream>>>(out, W3, bufA, N);
    k_agg<<<AB, THREADS, 0, stream>>>(bufA, rowp, deg, esrc, enorm, b3, out, N);
}